// Round 5
// baseline (734.834 us; speedup 1.0000x reference)
//
#include <hip/hip_runtime.h>

typedef unsigned short u16;
typedef unsigned int   u32;
typedef __bf16  bf16x8 __attribute__((ext_vector_type(8)));
typedef float   f32x4  __attribute__((ext_vector_type(4)));
typedef u32     u32x4  __attribute__((ext_vector_type(4)));

#define NN 65536      // nodes
#define NE 524288     // edges
#define FD 256        // feature dim

typedef const __attribute__((address_space(1))) void* gas_p;
typedef __attribute__((address_space(3))) void* las_p;
#define GLDS16(g, l) __builtin_amdgcn_global_load_lds((gas_p)(const void*)(g), (las_p)(void*)(l), 16, 0, 0)

__device__ __forceinline__ u16 f2bf(float f){
  u32 u = __float_as_uint(f);
  u += 0x7fffu + ((u >> 16) & 1u);
  return (u16)(u >> 16);
}
__device__ __forceinline__ float bf2f(u32 lo16){
  return __uint_as_float(lo16 << 16);
}

// ---------------- weight prep: fp32 (K,N=256) -> bf16 transposed (N=256,K) ----
__global__ __launch_bounds__(256) void prep_k(
    const float* __restrict__ w1a, const float* __restrict__ w1b,
    const float* __restrict__ w2a, const float* __restrict__ w2b,
    const float* __restrict__ w3a, const float* __restrict__ w3b,
    const float* __restrict__ w4a, const float* __restrict__ w4b,
    const float* __restrict__ wc1, u16* __restrict__ wT)
{
  int idx = blockIdx.x * 256 + threadIdx.x;   // 0 .. 655359
  const float* src; int base, K, local;
  if (idx < 131072){ src = w1a; base = 0; K = 512; local = idx; }
  else {
    local = idx - 131072;
    int j = local >> 16;       // 0..7
    local &= 65535;
    K = 256;
    base = 131072 + j * 65536;
    switch (j){
      case 0: src = w1b; break;
      case 1: src = w2a; break;
      case 2: src = w2b; break;
      case 3: src = w3a; break;
      case 4: src = w3b; break;
      case 5: src = w4a; break;
      case 6: src = w4b; break;
      default: src = wc1; break;
    }
  }
  int n = local & 255;
  int k = local >> 8;
  wT[base + n * K + k] = f2bf(src[k * 256 + n]);
}

// ---------------- CSR build ----------------
__global__ __launch_bounds__(256) void hist_k(const int* __restrict__ dst, int* __restrict__ deg){
  int e = blockIdx.x * 256 + threadIdx.x;
  atomicAdd(&deg[dst[e]], 1);
}

__global__ __launch_bounds__(1024) void scan_k(const int* __restrict__ deg, int* __restrict__ rs){
  __shared__ int part[1024];
  int t = threadIdx.x;
  int base = t * 64;
  int sum = 0;
  for (int i = 0; i < 64; ++i) sum += deg[base + i];
  part[t] = sum;
  __syncthreads();
  for (int off = 1; off < 1024; off <<= 1){
    int v = 0;
    if (t >= off) v = part[t - off];
    __syncthreads();
    part[t] += v;
    __syncthreads();
  }
  int run = part[t] - sum;          // exclusive prefix
  for (int i = 0; i < 64; ++i){ rs[base + i] = run; run += deg[base + i]; }
  if (t == 1023) rs[65536] = part[1023];
}

__global__ __launch_bounds__(256) void scat_k(
    const int* __restrict__ src, const int* __restrict__ dst,
    const int* __restrict__ rs, int* __restrict__ cursor, int* __restrict__ csr)
{
  int e = blockIdx.x * 256 + threadIdx.x;
  int d = dst[e];
  int pos = atomicAdd(&cursor[d], 1);
  csr[rs[d] + pos] = src[e];
}

// ------------- MFMA GEMM: C[M,256] = A[M,K] @ B[K,256], full-N tiles ---------
// Tile 128 x 256 per block (grid = M/128), 512 threads = 8 waves of 64x64
// (wm = w&1 row half, wn = w>>1 col quarter). BK=64. A/B staged to LDS via
// async global_load_lds (16B chunks, XOR-swizzled). A is read exactly once
// from HBM. Epilogue bounces C through LDS then nontemporal full-line stores
// (no L2 write-allocate fetch).
// MODE 0: plain. MODE 1: BN fold (p0=g,p1=be,p2=m,p3=v,p4=bb) + opt relu.
// MODE 2: bias (p0) + PReLU slope (p1).
template<int AF32, int MODE, int RELU, int K>
__global__ __launch_bounds__(512) void gemm_k(
    const void* __restrict__ Ap, const u16* __restrict__ Bt,
    u16* __restrict__ C,
    const float* __restrict__ p0, const float* __restrict__ p1,
    const float* __restrict__ p2, const float* __restrict__ p3,
    const float* __restrict__ p4)
{
  __shared__ u16 lds[32768];           // 64 KB: staging 48 KB / epilogue 64 KB
  u16* As = lds;                       // 1024 chunks of 16B (128 rows x 8), swizzled
  u16* Bs = lds + 8192;                // 2048 chunks of 16B (256 rows x 8), swizzled
  const int t    = threadIdx.x;
  const int lane = t & 63;
  const int w    = t >> 6;             // 0..7
  const int wm   = w & 1;              // row half (0..1)
  const int wn   = w >> 1;             // col quarter (0..3)
  const int m0   = blockIdx.x * 128;
  const int mrow = lane & 15;
  const int quad = lane >> 4;

  f32x4 acc[4][4];
  const f32x4 zero = {0.f, 0.f, 0.f, 0.f};
  #pragma unroll
  for (int i = 0; i < 4; ++i)
    #pragma unroll
    for (int j = 0; j < 4; ++j) acc[i][j] = zero;

  const u16* Ab = (const u16*)Ap;
  const float* Af = (const float*)Ap;

  for (int k0 = 0; k0 < K; k0 += 64){
    // ---- stage A tile (128 rows x 64 k = 1024 chunks) ----
    if (AF32){
      #pragma unroll
      for (int i = 0; i < 2; ++i){
        int p   = i * 512 + t;
        int row = p >> 3;
        // sequential global read, swizzled LDS placement
        const float* s = Af + (size_t)(m0 + row) * K + k0 + (p & 7) * 8;
        float4 x0 = *(const float4*)s;
        float4 x1 = *(const float4*)(s + 4);
        union { u32x4 q; u16 h[8]; } u;
        u.h[0] = f2bf(x0.x); u.h[1] = f2bf(x0.y); u.h[2] = f2bf(x0.z); u.h[3] = f2bf(x0.w);
        u.h[4] = f2bf(x1.x); u.h[5] = f2bf(x1.y); u.h[6] = f2bf(x1.z); u.h[7] = f2bf(x1.w);
        int dst = (p & ~7) | ((p & 7) ^ (row & 7));
        *(u32x4*)&As[dst * 8] = u.q;
      }
    } else {
      #pragma unroll
      for (int i = 0; i < 2; ++i){
        int p   = i * 512 + t;
        int row = p >> 3;
        int ch  = (p & 7) ^ (row & 7);     // swizzled source chunk
        GLDS16(Ab + (size_t)(m0 + row) * K + k0 + ch * 8, &As[p * 8]);
      }
    }
    // ---- stage B tile (256 n-rows x 64 k = 2048 chunks) ----
    #pragma unroll
    for (int i = 0; i < 4; ++i){
      int p   = i * 512 + t;
      int row = p >> 3;
      int ch  = (p & 7) ^ (row & 7);
      GLDS16(Bt + (size_t)row * K + k0 + ch * 8, &Bs[p * 8]);
    }
    __syncthreads();
    // ---- compute: 2 k-steps of 32 ----
    #pragma unroll
    for (int ks = 0; ks < 2; ++ks){
      bf16x8 af[4], bq[4];
      #pragma unroll
      for (int mi = 0; mi < 4; ++mi){
        int r  = wm * 64 + mi * 16 + mrow;
        int ch = (quad + ks * 4) ^ (r & 7);
        af[mi] = *(const bf16x8*)&As[(r * 8 + ch) * 8];
      }
      #pragma unroll
      for (int ni = 0; ni < 4; ++ni){
        int rb = wn * 64 + ni * 16 + mrow;
        int ch = (quad + ks * 4) ^ (rb & 7);
        bq[ni] = *(const bf16x8*)&Bs[(rb * 8 + ch) * 8];
      }
      #pragma unroll
      for (int mi = 0; mi < 4; ++mi)
        #pragma unroll
        for (int ni = 0; ni < 4; ++ni)
          acc[mi][ni] = __builtin_amdgcn_mfma_f32_16x16x32_bf16(af[mi], bq[ni], acc[mi][ni], 0, 0, 0);
    }
    __syncthreads();
  }

  // ---- epilogue: acc -> LDS (128x256 u16) -> nontemporal 16B stores ----
  #pragma unroll
  for (int ni = 0; ni < 4; ++ni){
    int c  = wn * 64 + ni * 16 + mrow;    // global col (N=256 full per block)
    float scale = 1.f, shift = 0.f, slope = 0.f;
    if (MODE == 1){
      float s = p0[c] * rsqrtf(p3[c] + 1e-5f);
      scale = s;
      shift = (p4[c] - p2[c]) * s + p1[c];
    }
    if (MODE == 2){ shift = p0[c]; slope = p1[c]; }
    #pragma unroll
    for (int mi = 0; mi < 4; ++mi){
      int rbase = wm * 64 + mi * 16 + quad * 4;
      #pragma unroll
      for (int reg = 0; reg < 4; ++reg){
        float v = acc[mi][ni][reg];
        if (MODE == 1){
          v = v * scale + shift;
          if (RELU) v = fmaxf(v, 0.f);
        }
        if (MODE == 2){
          v += shift;
          v = v > 0.f ? v : slope * v;
        }
        lds[(rbase + reg) * 256 + c] = f2bf(v);
      }
    }
  }
  __syncthreads();
  #pragma unroll
  for (int i = 0; i < 8; ++i){
    int p  = i * 512 + t;       // 4096 chunks of 16B (128 rows x 32 chunks)
    int r  = p >> 5;
    int ch = p & 31;
    u32x4 q = *(const u32x4*)&lds[r * 256 + ch * 8];
    __builtin_nontemporal_store(q, (u32x4*)&C[(size_t)(m0 + r) * 256 + ch * 8]);
  }
}

// ---------------- aggregation: t = relu((1+eps)*y + sum_{in-edges} y[src] + ba) ----
__global__ __launch_bounds__(256) void agg_k(
    const u16* __restrict__ y, const int* __restrict__ rs, const int* __restrict__ csr,
    const float* __restrict__ epsp, const float* __restrict__ bias, u16* __restrict__ tout)
{
  int node = blockIdx.x * 4 + (threadIdx.x >> 6);
  int lane = threadIdx.x & 63;
  int f0 = lane * 4;
  float e1 = 1.0f + epsp[0];
  int s0 = rs[node], s1 = rs[node + 1];
  float a0 = 0.f, a1 = 0.f, a2 = 0.f, a3 = 0.f;
  for (int e = s0; e < s1; ++e){
    int s = csr[e];
    uint2 v = *(const uint2*)(y + (size_t)s * 256 + f0);
    a0 += bf2f(v.x & 0xffffu);
    a1 += bf2f(v.x >> 16);
    a2 += bf2f(v.y & 0xffffu);
    a3 += bf2f(v.y >> 16);
  }
  uint2 own = *(const uint2*)(y + (size_t)node * 256 + f0);
  float4 bv = *(const float4*)(bias + f0);
  float r0 = fmaxf(e1 * bf2f(own.x & 0xffffu) + a0 + bv.x, 0.f);
  float r1 = fmaxf(e1 * bf2f(own.x >> 16)     + a1 + bv.y, 0.f);
  float r2 = fmaxf(e1 * bf2f(own.y & 0xffffu) + a2 + bv.z, 0.f);
  float r3 = fmaxf(e1 * bf2f(own.y >> 16)     + a3 + bv.w, 0.f);
  uint2 o;
  o.x = (u32)f2bf(r0) | ((u32)f2bf(r1) << 16);
  o.y = (u32)f2bf(r2) | ((u32)f2bf(r3) << 16);
  *(uint2*)(tout + (size_t)node * 256 + f0) = o;
}

// ---- layer-4 aggregation, only the 6400 gathered rows (gather commutes past BN)
__global__ __launch_bounds__(256) void agg_g(
    const u16* __restrict__ y, const int* __restrict__ rs, const int* __restrict__ csr,
    const float* __restrict__ epsp, const float* __restrict__ bias,
    const int* __restrict__ gidx, u16* __restrict__ tout)
{
  int gr   = blockIdx.x * 4 + (threadIdx.x >> 6);   // 0..6399
  int node = (gr / 200) * 2048 + gidx[gr];
  int lane = threadIdx.x & 63;
  int f0 = lane * 4;
  float e1 = 1.0f + epsp[0];
  int s0 = rs[node], s1 = rs[node + 1];
  float a0 = 0.f, a1 = 0.f, a2 = 0.f, a3 = 0.f;
  for (int e = s0; e < s1; ++e){
    int s = csr[e];
    uint2 v = *(const uint2*)(y + (size_t)s * 256 + f0);
    a0 += bf2f(v.x & 0xffffu);
    a1 += bf2f(v.x >> 16);
    a2 += bf2f(v.y & 0xffffu);
    a3 += bf2f(v.y >> 16);
  }
  uint2 own = *(const uint2*)(y + (size_t)node * 256 + f0);
  float4 bv = *(const float4*)(bias + f0);
  float r0 = fmaxf(e1 * bf2f(own.x & 0xffffu) + a0 + bv.x, 0.f);
  float r1 = fmaxf(e1 * bf2f(own.x >> 16)     + a1 + bv.y, 0.f);
  float r2 = fmaxf(e1 * bf2f(own.y & 0xffffu) + a2 + bv.z, 0.f);
  float r3 = fmaxf(e1 * bf2f(own.y >> 16)     + a3 + bv.w, 0.f);
  uint2 o;
  o.x = (u32)f2bf(r0) | ((u32)f2bf(r1) << 16);
  o.y = (u32)f2bf(r2) | ((u32)f2bf(r3) << 16);
  *(uint2*)(tout + (size_t)gr * 256 + f0) = o;
}

// ---------------- head: out[6400,2] = hc[6400,256] @ wc2[256,2] + bc2 ----------
__global__ __launch_bounds__(256) void head_k(
    const u16* __restrict__ hc, const float* __restrict__ wc2,
    const float* __restrict__ bc2, float* __restrict__ out)
{
  int row  = blockIdx.x * 4 + (threadIdx.x >> 6);
  int lane = threadIdx.x & 63;
  int f0   = lane * 4;
  uint2 hv = *(const uint2*)(hc + (size_t)row * 256 + f0);
  float h0 = bf2f(hv.x & 0xffffu), h1 = bf2f(hv.x >> 16);
  float h2 = bf2f(hv.y & 0xffffu), h3 = bf2f(hv.y >> 16);
  float4 wa = *(const float4*)(wc2 + f0 * 2);
  float4 wb = *(const float4*)(wc2 + f0 * 2 + 4);
  float acc0 = h0 * wa.x + h1 * wa.z + h2 * wb.x + h3 * wb.z;
  float acc1 = h0 * wa.y + h1 * wa.w + h2 * wb.y + h3 * wb.w;
  #pragma unroll
  for (int off = 32; off > 0; off >>= 1){
    acc0 += __shfl_xor(acc0, off);
    acc1 += __shfl_xor(acc1, off);
  }
  if (lane == 0){
    out[row * 2]     = acc0 + bc2[0];
    out[row * 2 + 1] = acc1 + bc2[1];
  }
}

extern "C" void kernel_launch(void* const* d_in, const int* in_sizes, int n_in,
                              void* d_out, int out_size, void* d_ws, size_t ws_size,
                              hipStream_t stream)
{
  const float* feat = (const float*)d_in[0];
  const int*   A    = (const int*)d_in[1];
  const int*   h1id = (const int*)d_in[2];
  const float* eps[4] = {(const float*)d_in[4],  (const float*)d_in[13], (const float*)d_in[22], (const float*)d_in[31]};
  const float* wa [4] = {(const float*)d_in[5],  (const float*)d_in[14], (const float*)d_in[23], (const float*)d_in[32]};
  const float* ba [4] = {(const float*)d_in[6],  (const float*)d_in[15], (const float*)d_in[24], (const float*)d_in[33]};
  const float* wb [4] = {(const float*)d_in[7],  (const float*)d_in[16], (const float*)d_in[25], (const float*)d_in[34]};
  const float* bb [4] = {(const float*)d_in[8],  (const float*)d_in[17], (const float*)d_in[26], (const float*)d_in[35]};
  const float* g  [4] = {(const float*)d_in[9],  (const float*)d_in[18], (const float*)d_in[27], (const float*)d_in[36]};
  const float* be [4] = {(const float*)d_in[10], (const float*)d_in[19], (const float*)d_in[28], (const float*)d_in[37]};
  const float* m  [4] = {(const float*)d_in[11], (const float*)d_in[20], (const float*)d_in[29], (const float*)d_in[38]};
  const float* v  [4] = {(const float*)d_in[12], (const float*)d_in[21], (const float*)d_in[30], (const float*)d_in[39]};
  const float* wc1 = (const float*)d_in[40];
  const float* bc1 = (const float*)d_in[41];
  const float* pa  = (const float*)d_in[42];
  const float* wc2 = (const float*)d_in[43];
  const float* bc2 = (const float*)d_in[44];

  char* ws = (char*)d_ws;
  u16* wT     = (u16*)(ws + 0);            // 655360 u16 = 1,310,720 B
  int* deg    = (int*)(ws + 1310720);      // 262,144 B
  int* rs     = (int*)(ws + 1572864);      // 65537 ints, pad to 262,400 B
  int* cursor = (int*)(ws + 1835264);      // 262,144 B
  int* csr    = (int*)(ws + 2097408);      // 2,097,152 B
  u16* ybuf   = (u16*)(ws + 4194560);      // 32 MB
  u16* tbuf   = (u16*)(ws + 37748992);     // 32 MB (also reused as compact t4)
  u16* hbuf   = (u16*)(ws + 71303424);     // 32 MB
  u16* h4     = (u16*)(ws + 104857856);    // 3.2 MB
  u16* hc     = (u16*)(ws + 108134656);    // 3.2 MB

  // wT sub-offsets (u16 elements)
  u16* w1aT = wT;            // [256][512]
  u16* w1bT = wT + 131072;
  u16* w2aT = wT + 196608;
  u16* w2bT = wT + 262144;
  u16* w3aT = wT + 327680;
  u16* w3bT = wT + 393216;
  u16* w4aT = wT + 458752;
  u16* w4bT = wT + 524288;
  u16* wc1T = wT + 589824;

  hipMemsetAsync(deg, 0, 65536 * 4, stream);
  hipMemsetAsync(cursor, 0, 65536 * 4, stream);
  prep_k<<<2560, 256, 0, stream>>>(wa[0], wb[0], wa[1], wb[1], wa[2], wb[2], wa[3], wb[3], wc1, wT);
  hist_k<<<NE / 256, 256, 0, stream>>>(A + NE, deg);
  scan_k<<<1, 1024, 0, stream>>>(deg, rs);
  scat_k<<<NE / 256, 256, 0, stream>>>(A, A + NE, rs, cursor, csr);

  const u16* waT[4] = {w1aT, w2aT, w3aT, w4aT};
  const u16* wbT[4] = {w1bT, w2bT, w3bT, w4bT};

  // layer 1 (A = feat fp32, K=512)
  gemm_k<1,0,0,512><<<512, 512, 0, stream>>>(feat, waT[0], ybuf,
      nullptr, nullptr, nullptr, nullptr, nullptr);
  agg_k<<<NN / 4, 256, 0, stream>>>(ybuf, rs, csr, eps[0], ba[0], tbuf);
  gemm_k<0,1,1,256><<<512, 512, 0, stream>>>(tbuf, wbT[0], hbuf,
      g[0], be[0], m[0], v[0], bb[0]);

  // layers 2,3
  for (int l = 1; l <= 2; ++l){
    gemm_k<0,0,0,256><<<512, 512, 0, stream>>>(hbuf, waT[l], ybuf,
        nullptr, nullptr, nullptr, nullptr, nullptr);
    agg_k<<<NN / 4, 256, 0, stream>>>(ybuf, rs, csr, eps[l], ba[l], tbuf);
    gemm_k<0,1,1,256><<<512, 512, 0, stream>>>(tbuf, wbT[l], hbuf,
        g[l], be[l], m[l], v[l], bb[l]);
  }

  // layer 4: aggregate only the 6400 gathered rows, then compact GEMMs
  gemm_k<0,0,0,256><<<512, 512, 0, stream>>>(hbuf, waT[3], ybuf,
      nullptr, nullptr, nullptr, nullptr, nullptr);
  agg_g<<<1600, 256, 0, stream>>>(ybuf, rs, csr, eps[3], ba[3], h1id, tbuf);
  gemm_k<0,1,0,256><<<50, 512, 0, stream>>>(tbuf, wbT[3], h4,
      g[3], be[3], m[3], v[3], bb[3]);

  // head: hc = PReLU(h4 @ wc1 + bc1); out = hc @ wc2 + bc2
  gemm_k<0,2,0,256><<<50, 512, 0, stream>>>(h4, wc1T, hc,
      bc1, pa, nullptr, nullptr, nullptr);
  head_k<<<1600, 256, 0, stream>>>(hc, wc2, bc2, (float*)d_out);

  (void)in_sizes; (void)n_in; (void)out_size; (void)ws_size;
}

// Round 6
// 628.633 us; speedup vs baseline: 1.1689x; 1.1689x over previous
//
#include <hip/hip_runtime.h>

typedef unsigned short u16;
typedef unsigned int   u32;
typedef __bf16  bf16x8 __attribute__((ext_vector_type(8)));
typedef float   f32x4  __attribute__((ext_vector_type(4)));
typedef u32     u32x4  __attribute__((ext_vector_type(4)));

#define NN 65536      // nodes
#define NE 524288     // edges
#define FD 256        // feature dim

typedef const __attribute__((address_space(1))) void* gas_p;
typedef __attribute__((address_space(3))) void* las_p;
#define GLDS16(g, l) __builtin_amdgcn_global_load_lds((gas_p)(const void*)(g), (las_p)(void*)(l), 16, 0, 0)

__device__ __forceinline__ u16 f2bf(float f){
  u32 u = __float_as_uint(f);
  u += 0x7fffu + ((u >> 16) & 1u);
  return (u16)(u >> 16);
}
__device__ __forceinline__ float bf2f(u32 lo16){
  return __uint_as_float(lo16 << 16);
}
__device__ __forceinline__ void acc8(float* a, uint4 v){
  a[0] += bf2f(v.x & 0xffffu); a[1] += bf2f(v.x >> 16);
  a[2] += bf2f(v.y & 0xffffu); a[3] += bf2f(v.y >> 16);
  a[4] += bf2f(v.z & 0xffffu); a[5] += bf2f(v.z >> 16);
  a[6] += bf2f(v.w & 0xffffu); a[7] += bf2f(v.w >> 16);
}

// ---------------- weight prep: fp32 (K,N=256) -> bf16 transposed (N=256,K) ----
__global__ __launch_bounds__(256) void prep_k(
    const float* __restrict__ w1a, const float* __restrict__ w1b,
    const float* __restrict__ w2a, const float* __restrict__ w2b,
    const float* __restrict__ w3a, const float* __restrict__ w3b,
    const float* __restrict__ w4a, const float* __restrict__ w4b,
    const float* __restrict__ wc1, u16* __restrict__ wT)
{
  int idx = blockIdx.x * 256 + threadIdx.x;   // 0 .. 655359
  const float* src; int base, K, local;
  if (idx < 131072){ src = w1a; base = 0; K = 512; local = idx; }
  else {
    local = idx - 131072;
    int j = local >> 16;       // 0..7
    local &= 65535;
    K = 256;
    base = 131072 + j * 65536;
    switch (j){
      case 0: src = w1b; break;
      case 1: src = w2a; break;
      case 2: src = w2b; break;
      case 3: src = w3a; break;
      case 4: src = w3b; break;
      case 5: src = w4a; break;
      case 6: src = w4b; break;
      default: src = wc1; break;
    }
  }
  int n = local & 255;
  int k = local >> 8;
  wT[base + n * K + k] = f2bf(src[k * 256 + n]);
}

// ---------------- CSR build ----------------
__global__ __launch_bounds__(256) void hist_k(const int* __restrict__ dst, int* __restrict__ deg){
  int e = blockIdx.x * 256 + threadIdx.x;
  atomicAdd(&deg[dst[e]], 1);
}

__global__ __launch_bounds__(1024) void scan_k(const int* __restrict__ deg, int* __restrict__ rs){
  __shared__ int part[1024];
  int t = threadIdx.x;
  int base = t * 64;
  int sum = 0;
  for (int i = 0; i < 64; ++i) sum += deg[base + i];
  part[t] = sum;
  __syncthreads();
  for (int off = 1; off < 1024; off <<= 1){
    int v = 0;
    if (t >= off) v = part[t - off];
    __syncthreads();
    part[t] += v;
    __syncthreads();
  }
  int run = part[t] - sum;          // exclusive prefix
  for (int i = 0; i < 64; ++i){ rs[base + i] = run; run += deg[base + i]; }
  if (t == 1023) rs[65536] = part[1023];
}

__global__ __launch_bounds__(256) void scat_k(
    const int* __restrict__ src, const int* __restrict__ dst,
    const int* __restrict__ rs, int* __restrict__ cursor, int* __restrict__ csr)
{
  int e = blockIdx.x * 256 + threadIdx.x;
  int d = dst[e];
  int pos = atomicAdd(&cursor[d], 1);
  csr[rs[d] + pos] = src[e];
}

// ------------- MFMA GEMM: C[M,256] = A[M,K] @ B[K,256], full-N tiles ---------
// Tile 128 x 256 per block (grid = M/128), 512 threads = 8 waves of 64x64.
// BK=64. A/B staged to LDS via async global_load_lds (16B chunks, XOR-swizzled).
// A read exactly once from HBM. Epilogue bounces C through LDS for full-line
// stores (regular stores: consumers re-read these buffers, keep them L2-warm).
// MODE 0: plain. MODE 1: BN fold (p0=g,p1=be,p2=m,p3=v,p4=bb) + opt relu.
// MODE 2: bias (p0) + PReLU slope (p1).
template<int AF32, int MODE, int RELU, int K>
__global__ __launch_bounds__(512) void gemm_k(
    const void* __restrict__ Ap, const u16* __restrict__ Bt,
    u16* __restrict__ C,
    const float* __restrict__ p0, const float* __restrict__ p1,
    const float* __restrict__ p2, const float* __restrict__ p3,
    const float* __restrict__ p4)
{
  __shared__ u16 lds[32768];           // 64 KB: staging 48 KB / epilogue 64 KB
  u16* As = lds;                       // 1024 chunks of 16B (128 rows x 8), swizzled
  u16* Bs = lds + 8192;                // 2048 chunks of 16B (256 rows x 8), swizzled
  const int t    = threadIdx.x;
  const int lane = t & 63;
  const int w    = t >> 6;             // 0..7
  const int wm   = w & 1;              // row half (0..1)
  const int wn   = w >> 1;             // col quarter (0..3)
  const int m0   = blockIdx.x * 128;
  const int mrow = lane & 15;
  const int quad = lane >> 4;

  f32x4 acc[4][4];
  const f32x4 zero = {0.f, 0.f, 0.f, 0.f};
  #pragma unroll
  for (int i = 0; i < 4; ++i)
    #pragma unroll
    for (int j = 0; j < 4; ++j) acc[i][j] = zero;

  const u16* Ab = (const u16*)Ap;
  const float* Af = (const float*)Ap;

  for (int k0 = 0; k0 < K; k0 += 64){
    // ---- stage A tile (128 rows x 64 k = 1024 chunks) ----
    if (AF32){
      #pragma unroll
      for (int i = 0; i < 2; ++i){
        int p   = i * 512 + t;
        int row = p >> 3;
        const float* s = Af + (size_t)(m0 + row) * K + k0 + (p & 7) * 8;
        float4 x0 = *(const float4*)s;
        float4 x1 = *(const float4*)(s + 4);
        union { u32x4 q; u16 h[8]; } u;
        u.h[0] = f2bf(x0.x); u.h[1] = f2bf(x0.y); u.h[2] = f2bf(x0.z); u.h[3] = f2bf(x0.w);
        u.h[4] = f2bf(x1.x); u.h[5] = f2bf(x1.y); u.h[6] = f2bf(x1.z); u.h[7] = f2bf(x1.w);
        int dst = (p & ~7) | ((p & 7) ^ (row & 7));
        *(u32x4*)&As[dst * 8] = u.q;
      }
    } else {
      #pragma unroll
      for (int i = 0; i < 2; ++i){
        int p   = i * 512 + t;
        int row = p >> 3;
        int ch  = (p & 7) ^ (row & 7);     // swizzled source chunk
        GLDS16(Ab + (size_t)(m0 + row) * K + k0 + ch * 8, &As[p * 8]);
      }
    }
    // ---- stage B tile (256 n-rows x 64 k = 2048 chunks) ----
    #pragma unroll
    for (int i = 0; i < 4; ++i){
      int p   = i * 512 + t;
      int row = p >> 3;
      int ch  = (p & 7) ^ (row & 7);
      GLDS16(Bt + (size_t)row * K + k0 + ch * 8, &Bs[p * 8]);
    }
    __syncthreads();
    // ---- compute: 2 k-steps of 32 ----
    #pragma unroll
    for (int ks = 0; ks < 2; ++ks){
      bf16x8 af[4], bq[4];
      #pragma unroll
      for (int mi = 0; mi < 4; ++mi){
        int r  = wm * 64 + mi * 16 + mrow;
        int ch = (quad + ks * 4) ^ (r & 7);
        af[mi] = *(const bf16x8*)&As[(r * 8 + ch) * 8];
      }
      #pragma unroll
      for (int ni = 0; ni < 4; ++ni){
        int rb = wn * 64 + ni * 16 + mrow;
        int ch = (quad + ks * 4) ^ (rb & 7);
        bq[ni] = *(const bf16x8*)&Bs[(rb * 8 + ch) * 8];
      }
      #pragma unroll
      for (int mi = 0; mi < 4; ++mi)
        #pragma unroll
        for (int ni = 0; ni < 4; ++ni)
          acc[mi][ni] = __builtin_amdgcn_mfma_f32_16x16x32_bf16(af[mi], bq[ni], acc[mi][ni], 0, 0, 0);
    }
    __syncthreads();
  }

  // ---- epilogue: acc -> LDS (128x256 u16) -> coalesced 16B stores ----
  #pragma unroll
  for (int ni = 0; ni < 4; ++ni){
    int c  = wn * 64 + ni * 16 + mrow;    // global col (N=256 full per block)
    float scale = 1.f, shift = 0.f, slope = 0.f;
    if (MODE == 1){
      float s = p0[c] * rsqrtf(p3[c] + 1e-5f);
      scale = s;
      shift = (p4[c] - p2[c]) * s + p1[c];
    }
    if (MODE == 2){ shift = p0[c]; slope = p1[c]; }
    #pragma unroll
    for (int mi = 0; mi < 4; ++mi){
      int rbase = wm * 64 + mi * 16 + quad * 4;
      #pragma unroll
      for (int reg = 0; reg < 4; ++reg){
        float v = acc[mi][ni][reg];
        if (MODE == 1){
          v = v * scale + shift;
          if (RELU) v = fmaxf(v, 0.f);
        }
        if (MODE == 2){
          v += shift;
          v = v > 0.f ? v : slope * v;
        }
        lds[(rbase + reg) * 256 + c] = f2bf(v);
      }
    }
  }
  __syncthreads();
  #pragma unroll
  for (int i = 0; i < 8; ++i){
    int p  = i * 512 + t;       // 4096 chunks of 16B (128 rows x 32 chunks)
    int r  = p >> 5;
    int ch = p & 31;
    u32x4 q = *(const u32x4*)&lds[r * 256 + ch * 8];
    *(u32x4*)&C[(size_t)(m0 + r) * 256 + ch * 8] = q;
  }
}

// ------- aggregation: t = relu((1+eps)*y + sum_{in-edges} y[src] + ba) -------
// 2 nodes per wave (32 lanes x 16B = one 512B row per edge). Edge loop
// unrolled x4 with csr indices batch-loaded first -> >=4 independent 16B
// loads in flight per lane (MLP). GATH=1: only the 6400 gathered rows.
template<int GATH>
__global__ __launch_bounds__(256) void agg_k(
    const u16* __restrict__ y, const int* __restrict__ rs, const int* __restrict__ csr,
    const float* __restrict__ epsp, const float* __restrict__ bias,
    const int* __restrict__ gidx, u16* __restrict__ tout)
{
  int sub    = threadIdx.x >> 5;            // 0..7 node slot in block
  int lane32 = threadIdx.x & 31;
  int idx    = blockIdx.x * 8 + sub;
  int node;
  if (GATH) node = (idx / 200) * 2048 + gidx[idx];
  else      node = idx;
  int f0 = lane32 * 8;                      // 8 u16 = 16 B per lane
  float e1 = 1.0f + epsp[0];
  int s0 = rs[node], s1 = rs[node + 1];
  float a[8] = {0.f,0.f,0.f,0.f,0.f,0.f,0.f,0.f};
  int e = s0;
  for (; e + 4 <= s1; e += 4){
    int sa = csr[e], sb = csr[e+1], sc = csr[e+2], sd = csr[e+3];
    uint4 va = *(const uint4*)(y + (size_t)sa * 256 + f0);
    uint4 vb = *(const uint4*)(y + (size_t)sb * 256 + f0);
    uint4 vc = *(const uint4*)(y + (size_t)sc * 256 + f0);
    uint4 vd = *(const uint4*)(y + (size_t)sd * 256 + f0);
    acc8(a, va); acc8(a, vb); acc8(a, vc); acc8(a, vd);
  }
  for (; e < s1; ++e){
    int s = csr[e];
    acc8(a, *(const uint4*)(y + (size_t)s * 256 + f0));
  }
  uint4 own = *(const uint4*)(y + (size_t)node * 256 + f0);
  float ow[8];
  ow[0] = bf2f(own.x & 0xffffu); ow[1] = bf2f(own.x >> 16);
  ow[2] = bf2f(own.y & 0xffffu); ow[3] = bf2f(own.y >> 16);
  ow[4] = bf2f(own.z & 0xffffu); ow[5] = bf2f(own.z >> 16);
  ow[6] = bf2f(own.w & 0xffffu); ow[7] = bf2f(own.w >> 16);
  float4 b0 = *(const float4*)(bias + f0);
  float4 b1 = *(const float4*)(bias + f0 + 4);
  float r[8];
  r[0] = fmaxf(e1 * ow[0] + a[0] + b0.x, 0.f);
  r[1] = fmaxf(e1 * ow[1] + a[1] + b0.y, 0.f);
  r[2] = fmaxf(e1 * ow[2] + a[2] + b0.z, 0.f);
  r[3] = fmaxf(e1 * ow[3] + a[3] + b0.w, 0.f);
  r[4] = fmaxf(e1 * ow[4] + a[4] + b1.x, 0.f);
  r[5] = fmaxf(e1 * ow[5] + a[5] + b1.y, 0.f);
  r[6] = fmaxf(e1 * ow[6] + a[6] + b1.z, 0.f);
  r[7] = fmaxf(e1 * ow[7] + a[7] + b1.w, 0.f);
  uint4 o;
  o.x = (u32)f2bf(r[0]) | ((u32)f2bf(r[1]) << 16);
  o.y = (u32)f2bf(r[2]) | ((u32)f2bf(r[3]) << 16);
  o.z = (u32)f2bf(r[4]) | ((u32)f2bf(r[5]) << 16);
  o.w = (u32)f2bf(r[6]) | ((u32)f2bf(r[7]) << 16);
  *(uint4*)(tout + (size_t)idx * 256 + f0) = o;
}

// ---------------- head: out[6400,2] = hc[6400,256] @ wc2[256,2] + bc2 ----------
__global__ __launch_bounds__(256) void head_k(
    const u16* __restrict__ hc, const float* __restrict__ wc2,
    const float* __restrict__ bc2, float* __restrict__ out)
{
  int row  = blockIdx.x * 4 + (threadIdx.x >> 6);
  int lane = threadIdx.x & 63;
  int f0   = lane * 4;
  uint2 hv = *(const uint2*)(hc + (size_t)row * 256 + f0);
  float h0 = bf2f(hv.x & 0xffffu), h1 = bf2f(hv.x >> 16);
  float h2 = bf2f(hv.y & 0xffffu), h3 = bf2f(hv.y >> 16);
  float4 wa = *(const float4*)(wc2 + f0 * 2);
  float4 wb = *(const float4*)(wc2 + f0 * 2 + 4);
  float acc0 = h0 * wa.x + h1 * wa.z + h2 * wb.x + h3 * wb.z;
  float acc1 = h0 * wa.y + h1 * wa.w + h2 * wb.y + h3 * wb.w;
  #pragma unroll
  for (int off = 32; off > 0; off >>= 1){
    acc0 += __shfl_xor(acc0, off);
    acc1 += __shfl_xor(acc1, off);
  }
  if (lane == 0){
    out[row * 2]     = acc0 + bc2[0];
    out[row * 2 + 1] = acc1 + bc2[1];
  }
}

extern "C" void kernel_launch(void* const* d_in, const int* in_sizes, int n_in,
                              void* d_out, int out_size, void* d_ws, size_t ws_size,
                              hipStream_t stream)
{
  const float* feat = (const float*)d_in[0];
  const int*   A    = (const int*)d_in[1];
  const int*   h1id = (const int*)d_in[2];
  const float* eps[4] = {(const float*)d_in[4],  (const float*)d_in[13], (const float*)d_in[22], (const float*)d_in[31]};
  const float* wa [4] = {(const float*)d_in[5],  (const float*)d_in[14], (const float*)d_in[23], (const float*)d_in[32]};
  const float* ba [4] = {(const float*)d_in[6],  (const float*)d_in[15], (const float*)d_in[24], (const float*)d_in[33]};
  const float* wb [4] = {(const float*)d_in[7],  (const float*)d_in[16], (const float*)d_in[25], (const float*)d_in[34]};
  const float* bb [4] = {(const float*)d_in[8],  (const float*)d_in[17], (const float*)d_in[26], (const float*)d_in[35]};
  const float* g  [4] = {(const float*)d_in[9],  (const float*)d_in[18], (const float*)d_in[27], (const float*)d_in[36]};
  const float* be [4] = {(const float*)d_in[10], (const float*)d_in[19], (const float*)d_in[28], (const float*)d_in[37]};
  const float* m  [4] = {(const float*)d_in[11], (const float*)d_in[20], (const float*)d_in[29], (const float*)d_in[38]};
  const float* v  [4] = {(const float*)d_in[12], (const float*)d_in[21], (const float*)d_in[30], (const float*)d_in[39]};
  const float* wc1 = (const float*)d_in[40];
  const float* bc1 = (const float*)d_in[41];
  const float* pa  = (const float*)d_in[42];
  const float* wc2 = (const float*)d_in[43];
  const float* bc2 = (const float*)d_in[44];

  char* ws = (char*)d_ws;
  u16* wT     = (u16*)(ws + 0);            // 655360 u16 = 1,310,720 B
  int* deg    = (int*)(ws + 1310720);      // 262,144 B
  int* rs     = (int*)(ws + 1572864);      // 65537 ints, pad to 262,400 B
  int* cursor = (int*)(ws + 1835264);      // 262,144 B
  int* csr    = (int*)(ws + 2097408);      // 2,097,152 B
  u16* ybuf   = (u16*)(ws + 4194560);      // 32 MB
  u16* tbuf   = (u16*)(ws + 37748992);     // 32 MB (also reused as compact t4)
  u16* hbuf   = (u16*)(ws + 71303424);     // 32 MB
  u16* h4     = (u16*)(ws + 104857856);    // 3.2 MB
  u16* hc     = (u16*)(ws + 108134656);    // 3.2 MB

  // wT sub-offsets (u16 elements)
  u16* w1aT = wT;            // [256][512]
  u16* w1bT = wT + 131072;
  u16* w2aT = wT + 196608;
  u16* w2bT = wT + 262144;
  u16* w3aT = wT + 327680;
  u16* w3bT = wT + 393216;
  u16* w4aT = wT + 458752;
  u16* w4bT = wT + 524288;
  u16* wc1T = wT + 589824;

  hipMemsetAsync(deg, 0, 65536 * 4, stream);
  hipMemsetAsync(cursor, 0, 65536 * 4, stream);
  prep_k<<<2560, 256, 0, stream>>>(wa[0], wb[0], wa[1], wb[1], wa[2], wb[2], wa[3], wb[3], wc1, wT);
  hist_k<<<NE / 256, 256, 0, stream>>>(A + NE, deg);
  scan_k<<<1, 1024, 0, stream>>>(deg, rs);
  scat_k<<<NE / 256, 256, 0, stream>>>(A, A + NE, rs, cursor, csr);

  const u16* waT[4] = {w1aT, w2aT, w3aT, w4aT};
  const u16* wbT[4] = {w1bT, w2bT, w3bT, w4bT};

  // layer 1 (A = feat fp32, K=512)
  gemm_k<1,0,0,512><<<512, 512, 0, stream>>>(feat, waT[0], ybuf,
      nullptr, nullptr, nullptr, nullptr, nullptr);
  agg_k<0><<<NN / 8, 256, 0, stream>>>(ybuf, rs, csr, eps[0], ba[0], nullptr, tbuf);
  gemm_k<0,1,1,256><<<512, 512, 0, stream>>>(tbuf, wbT[0], hbuf,
      g[0], be[0], m[0], v[0], bb[0]);

  // layers 2,3
  for (int l = 1; l <= 2; ++l){
    gemm_k<0,0,0,256><<<512, 512, 0, stream>>>(hbuf, waT[l], ybuf,
        nullptr, nullptr, nullptr, nullptr, nullptr);
    agg_k<0><<<NN / 8, 256, 0, stream>>>(ybuf, rs, csr, eps[l], ba[l], nullptr, tbuf);
    gemm_k<0,1,1,256><<<512, 512, 0, stream>>>(tbuf, wbT[l], hbuf,
        g[l], be[l], m[l], v[l], bb[l]);
  }

  // layer 4: aggregate only the 6400 gathered rows, then compact GEMMs
  gemm_k<0,0,0,256><<<512, 512, 0, stream>>>(hbuf, waT[3], ybuf,
      nullptr, nullptr, nullptr, nullptr, nullptr);
  agg_k<1><<<800, 256, 0, stream>>>(ybuf, rs, csr, eps[3], ba[3], h1id, tbuf);
  gemm_k<0,1,0,256><<<50, 512, 0, stream>>>(tbuf, wbT[3], h4,
      g[3], be[3], m[3], v[3], bb[3]);

  // head: hc = PReLU(h4 @ wc1 + bc1); out = hc @ wc2 + bc2
  gemm_k<0,2,0,256><<<50, 512, 0, stream>>>(h4, wc1T, hc,
      bc1, pa, nullptr, nullptr, nullptr);
  head_k<<<1600, 256, 0, stream>>>(hc, wc2, bc2, (float*)d_out);

  (void)in_sizes; (void)n_in; (void)out_size; (void)ws_size;
}